// Round 9
// baseline (944.964 us; speedup 1.0000x reference)
//
#include <hip/hip_runtime.h>

#define S_LEN 2048
#define HID 64

typedef float f32x4 __attribute__((ext_vector_type(4)));
typedef float f32x2 __attribute__((ext_vector_type(2)));

__device__ __forceinline__ float rlane(float v, int l) {
    return __int_as_float(__builtin_amdgcn_readlane(__float_as_int(v), l));
}
__device__ __forceinline__ f32x2 lo2(f32x4 v) { return __builtin_shufflevector(v, v, 0, 1); }
__device__ __forceinline__ f32x2 hi2(f32x4 v) { return __builtin_shufflevector(v, v, 2, 3); }

// v += dpp_moved(v); bound_ctrl=1 -> OOB lanes read 0.
template<int CTRL, int RM>
__device__ __forceinline__ float dpp_add(float v) {
    int t = __builtin_amdgcn_update_dpp(0, __float_as_int(v), CTRL, RM, 0xF, true);
    return v + __int_as_float(t);
}

// sum across 64 lanes -> uniform scalar, VALU-only.
__device__ __forceinline__ float wave_sum(float v) {
    v = dpp_add<0x111, 0xF>(v);  // row_shr:1
    v = dpp_add<0x112, 0xF>(v);  // row_shr:2
    v = dpp_add<0x114, 0xF>(v);  // row_shr:4
    v = dpp_add<0x118, 0xF>(v);  // row_shr:8
    v = dpp_add<0x142, 0xA>(v);  // row_bcast:15
    v = dpp_add<0x143, 0xC>(v);  // row_bcast:31 -> lane63 holds total
    return rlane(v, 63);
}

// v += quad_perm(v): xor1 = [1,0,3,2] = 0xB1, xor2 = [2,3,0,1] = 0x4E
template<int CTRL>
__device__ __forceinline__ float qp_add(float v) {
    int t = __builtin_amdgcn_update_dpp(0, __float_as_int(v), CTRL, 0xF, 0xF, true);
    return v + __int_as_float(t);
}

__global__ __launch_bounds__(256, 2) void rnn_garch_kernel(
    const float* __restrict__ res,   // (B, S)
    const float* __restrict__ Wih,   // (64, 2)
    const float* __restrict__ bih,   // (64,)
    const float* __restrict__ Whh,   // (64, 64)
    const float* __restrict__ bhh,   // (64,)
    const float* __restrict__ fcw,   // (64,)
    const float* __restrict__ fcb,   // (1,)
    float* __restrict__ out)         // (B, S)
{
    const int lane = threadIdx.x & 63;
    const int wave = threadIdx.x >> 6;
    const int b = blockIdx.x * 4 + wave;
    const int g = lane >> 2;   // output group: outputs {g, g+16, g+32, g+48}
    const int p = lane & 3;    // K-chunk: k in [16p, 16p+16)

    const float* __restrict__ row = res + (size_t)b * S_LEN;
    float* __restrict__ orow = out + (size_t)b * S_LEN;

    // per-wave h buffer (wave-private; DS ops within a wave are ordered)
    __shared__ __align__(16) float hb[4][HID];

    // W4[4m+j] = Whh[16m+g][16p+4j .. +3] : contiguous float4 gather.
    // Consumed as two k-pairs (lo2/hi2) against natural h pairs -> no splats.
    f32x4 W4[16];
#pragma unroll
    for (int m = 0; m < 4; ++m) {
        const float* wsrc = Whh + ((m << 4) + g) * HID + (p << 4);
#pragma unroll
        for (int j = 0; j < 4; ++j) W4[(m << 2) + j] = *(const f32x4*)(wsrc + (j << 2));
    }
    // Pin: opaque to the compiler -> cannot be re-loaded/spilled in-loop.
    asm("" : "+v"(W4[0]), "+v"(W4[1]), "+v"(W4[2]), "+v"(W4[3]),
             "+v"(W4[4]), "+v"(W4[5]), "+v"(W4[6]), "+v"(W4[7]),
             "+v"(W4[8]), "+v"(W4[9]), "+v"(W4[10]), "+v"(W4[11]),
             "+v"(W4[12]), "+v"(W4[13]), "+v"(W4[14]), "+v"(W4[15]));

    // per-lane epilogue params at outputs o_m = 16m+g
    const int o0 = g, o1 = 16 + g, o2 = 32 + g, o3 = 48 + g;
    const f32x2 wih0q01 = {Wih[o0 * 2], Wih[o1 * 2]};
    const f32x2 wih0q23 = {Wih[o2 * 2], Wih[o3 * 2]};
    const f32x2 wih1q01 = {Wih[o0 * 2 + 1], Wih[o1 * 2 + 1]};
    const f32x2 wih1q23 = {Wih[o2 * 2 + 1], Wih[o3 * 2 + 1]};
    const f32x2 basbq01 = {bih[o0] + bhh[o0], bih[o1] + bhh[o1]};
    const f32x2 basbq23 = {bih[o2] + bhh[o2], bih[o3] + bhh[o3]};
    // fc weights pre-scaled by 0.25: each output summed 4x across p-groups
    const f32x2 fwq01   = {fcw[o0] * 0.25f, fcw[o1] * 0.25f};
    const f32x2 fwq23   = {fcw[o2] * 0.25f, fcw[o3] * 0.25f};
    const float fb = fcb[0];

    // ---- sigma0 = var(row, ddof=1) ----
    float s1 = 0.f, s2 = 0.f;
#pragma unroll 8
    for (int i = 0; i < S_LEN / 64; ++i) {
        const float x = row[i * 64 + lane];
        s1 += x;
        s2 = fmaf(x, x, s2);
    }
    s1 = wave_sum(s1);
    s2 = wave_sum(s2);
    const float mean = s1 * (1.0f / S_LEN);
    float sigma = (s2 - s1 * mean) * (1.0f / (S_LEN - 1));

    float vout = (lane == 0) ? sigma : 0.f;   // out[b][0] = sigma0

    // eps^2 double-buffer: squared once per 64-step window
    float en = row[64 + lane];
    float eq = row[lane] * row[lane];

    float* hbw = &hb[wave][0];
    const f32x4* hbq = (const f32x4*)hbw + (p << 2);  // quads 4p..4p+3
    float* hwr = &hb[wave][(p << 4) + g];             // writes h[16p+g]

    // h_0 = 0: loop-carried hq regs start at zero (no LDS init needed)
    f32x4 hq0 = {0,0,0,0}, hq1 = {0,0,0,0}, hq2 = {0,0,0,0}, hq3 = {0,0,0,0};

// two pk_fma per weight float4 against natural h pairs
#define MJ(M, J, HQ) { \
    acc##M = __builtin_elementwise_fma(lo2(W4[(M<<2)+J]), lo2(HQ), acc##M); \
    acc##M = __builtin_elementwise_fma(hi2(W4[(M<<2)+J]), hi2(HQ), acc##M); }

#pragma unroll 2
    for (int t = 1; t < S_LEN; ++t) {
        const int idx = (t - 1) & 63;
        if (idx == 0 && t > 1) {            // wave-uniform window advance
            eq = en * en;
            const int nb = ((t - 1) >> 6) + 1;
            if (nb < S_LEN / 64) en = row[nb * 64 + lane];
        }
        const float e2 = rlane(eq, idx);

        // matvec partials over this lane's K-chunk (4 independent chains)
        f32x2 acc0 = {0,0}, acc1 = {0,0}, acc2 = {0,0}, acc3 = {0,0};
        MJ(0,0,hq0) MJ(0,1,hq1) MJ(0,2,hq2) MJ(0,3,hq3)
        MJ(1,0,hq0) MJ(1,1,hq1) MJ(1,2,hq2) MJ(1,3,hq3)
        MJ(2,0,hq0) MJ(2,1,hq1) MJ(2,2,hq2) MJ(2,3,hq3)
        MJ(3,0,hq0) MJ(3,1,hq1) MJ(3,2,hq2) MJ(3,3,hq3)

        // horizontal add (even-k + odd-k) -> 4 scalars, packed in pairs
        f32x2 y01 = {acc0.x + acc0.y, acc1.x + acc1.y};
        f32x2 y23 = {acc2.x + acc2.y, acc3.x + acc3.y};

        // reduce across K-chunks (lane bits 0-1): quad_perm xor1 + xor2
        y01.x = qp_add<0xB1>(y01.x); y01.y = qp_add<0xB1>(y01.y);
        y23.x = qp_add<0xB1>(y23.x); y23.y = qp_add<0xB1>(y23.y);
        y01.x = qp_add<0x4E>(y01.x); y01.y = qp_add<0x4E>(y01.y);
        y23.x = qp_add<0x4E>(y23.x); y23.y = qp_add<0x4E>(y23.y);

        // epilogue: + b + eps^2*Wih0 + sigma_{t-1}*Wih1 (sigma enters LATE)
        const f32x2 e2v = {e2, e2};
        const f32x2 sgv = {sigma, sigma};
        y01 += basbq01;
        y23 += basbq23;
        y01 = __builtin_elementwise_fma(e2v, wih0q01, y01);
        y23 = __builtin_elementwise_fma(e2v, wih0q23, y23);
        y01 = __builtin_elementwise_fma(sgv, wih1q01, y01);
        y23 = __builtin_elementwise_fma(sgv, wih1q23, y23);

        // write h[16p+g], then IMMEDIATELY prefetch next step's h quads;
        // their ~130cyc latency overlaps the wave_sum/softplus tail below
        const float hvx = (lane & 2) ? y23.x : y01.x;
        const float hvy = (lane & 2) ? y23.y : y01.y;
        *hwr = (lane & 1) ? hvy : hvx;
        hq0 = hbq[0]; hq1 = hbq[1]; hq2 = hbq[2]; hq3 = hbq[3];

        // x = fc . h + fc_b (fw pre-scaled by 0.25)
        f32x2 sdot = y01 * fwq01;
        sdot = __builtin_elementwise_fma(y23, fwq23, sdot);
        const float x = wave_sum(sdot.x + sdot.y) + fb;

        // softplus(x) = max(x,0) + log(1 + exp(-|x|))
        const float ee = __expf(-fabsf(x));
        sigma = fmaxf(x, 0.f) + __logf(1.0f + ee) + 1e-6f;

        // stage sigma_t into lane (t&63); coalesced store each 64 steps
        if ((t & 63) == lane) vout = sigma;
        if ((t & 63) == 63) orow[(t - 63) + lane] = vout;
    }
#undef MJ
}

extern "C" void kernel_launch(void* const* d_in, const int* in_sizes, int n_in,
                              void* d_out, int out_size, void* d_ws, size_t ws_size,
                              hipStream_t stream) {
    const float* res = (const float*)d_in[0];
    const float* Wih = (const float*)d_in[1];
    const float* bih = (const float*)d_in[2];
    const float* Whh = (const float*)d_in[3];
    const float* bhh = (const float*)d_in[4];
    const float* fcw = (const float*)d_in[5];
    const float* fcb = (const float*)d_in[6];
    float* out = (float*)d_out;

    const int B = 2048;
    dim3 grid(B / 4), block(256);
    hipLaunchKernelGGL(rnn_garch_kernel, grid, block, 0, stream,
                       res, Wih, bih, Whh, bhh, fcw, fcb, out);
}

// Round 10
// 944.094 us; speedup vs baseline: 1.0009x; 1.0009x over previous
//
#include <hip/hip_runtime.h>

#define S_LEN 2048
#define HID 64

typedef float f32x4 __attribute__((ext_vector_type(4)));
typedef float f32x2 __attribute__((ext_vector_type(2)));

__device__ __forceinline__ float rlane(float v, int l) {
    return __int_as_float(__builtin_amdgcn_readlane(__float_as_int(v), l));
}
__device__ __forceinline__ f32x2 lo2(f32x4 v) { return __builtin_shufflevector(v, v, 0, 1); }
__device__ __forceinline__ f32x2 hi2(f32x4 v) { return __builtin_shufflevector(v, v, 2, 3); }

// v += dpp_moved(v); bound_ctrl=1 -> OOB lanes read 0.
template<int CTRL, int RM>
__device__ __forceinline__ float dpp_add(float v) {
    int t = __builtin_amdgcn_update_dpp(0, __float_as_int(v), CTRL, RM, 0xF, true);
    return v + __int_as_float(t);
}

// sum across 64 lanes -> uniform scalar (init only).
__device__ __forceinline__ float wave_sum(float v) {
    v = dpp_add<0x111, 0xF>(v);
    v = dpp_add<0x112, 0xF>(v);
    v = dpp_add<0x114, 0xF>(v);
    v = dpp_add<0x118, 0xF>(v);
    v = dpp_add<0x142, 0xA>(v);
    v = dpp_add<0x143, 0xC>(v);
    return rlane(v, 63);
}

// v += quad_perm(v): xor1 = 0xB1, xor2 = 0x4E
template<int CTRL>
__device__ __forceinline__ float qp_add(float v) {
    int t = __builtin_amdgcn_update_dpp(0, __float_as_int(v), CTRL, 0xF, 0xF, true);
    return v + __int_as_float(t);
}

__global__ __launch_bounds__(256, 2) void rnn_garch_kernel(
    const float* __restrict__ res,   // (B, S)
    const float* __restrict__ Wih,   // (64, 2)
    const float* __restrict__ bih,   // (64,)
    const float* __restrict__ Whh,   // (64, 64)
    const float* __restrict__ bhh,   // (64,)
    const float* __restrict__ fcw,   // (64,)
    const float* __restrict__ fcb,   // (1,)
    float* __restrict__ out)         // (B, S)
{
    const int lane = threadIdx.x & 63;
    const int wave = threadIdx.x >> 6;
    const int b = blockIdx.x * 4 + wave;
    const int g = lane >> 2;   // output group: outputs {g, g+16, g+32, g+48}
    const int p = lane & 3;    // K-chunk: k in [16p, 16p+16)

    const float* __restrict__ row = res + (size_t)b * S_LEN;
    float* __restrict__ orow = out + (size_t)b * S_LEN;

    // per-wave h buffer (wave-private; DS ops within a wave are ordered)
    __shared__ __align__(16) float hb[4][HID];

    // W4[4m+j] = Whh[16m+g][16p+4j .. +3] : contiguous float4 gather.
    f32x4 W4[16];
#pragma unroll
    for (int m = 0; m < 4; ++m) {
        const float* wsrc = Whh + ((m << 4) + g) * HID + (p << 4);
#pragma unroll
        for (int j = 0; j < 4; ++j) W4[(m << 2) + j] = *(const f32x4*)(wsrc + (j << 2));
    }
    asm("" : "+v"(W4[0]), "+v"(W4[1]), "+v"(W4[2]), "+v"(W4[3]),
             "+v"(W4[4]), "+v"(W4[5]), "+v"(W4[6]), "+v"(W4[7]),
             "+v"(W4[8]), "+v"(W4[9]), "+v"(W4[10]), "+v"(W4[11]),
             "+v"(W4[12]), "+v"(W4[13]), "+v"(W4[14]), "+v"(W4[15]));

    // u = W_hh^T fc (this lane's K-chunk), c0 = fc.Wih[:,0], c1 = fc.Wih[:,1],
    // cb = fc.(bih+bhh) + fcb  -- the sigma-decoupling constants
    f32x4 uq0 = {0,0,0,0}, uq1 = {0,0,0,0}, uq2 = {0,0,0,0}, uq3 = {0,0,0,0};
    float c0 = 0.f, c1 = 0.f, cb = 0.f;
    for (int j = 0; j < HID; ++j) {
        const float f = fcw[j];
        const float* wrow = Whh + j * HID + (p << 4);
        const f32x4 fv = {f, f, f, f};
        uq0 = __builtin_elementwise_fma(fv, *(const f32x4*)(wrow + 0),  uq0);
        uq1 = __builtin_elementwise_fma(fv, *(const f32x4*)(wrow + 4),  uq1);
        uq2 = __builtin_elementwise_fma(fv, *(const f32x4*)(wrow + 8),  uq2);
        uq3 = __builtin_elementwise_fma(fv, *(const f32x4*)(wrow + 12), uq3);
        c0 = fmaf(f, Wih[j * 2], c0);
        c1 = fmaf(f, Wih[j * 2 + 1], c1);
        cb = fmaf(f, bih[j] + bhh[j], cb);
    }
    cb += fcb[0];

    // per-lane epilogue params at outputs o_m = 16m+g
    const int o0 = g, o1 = 16 + g, o2 = 32 + g, o3 = 48 + g;
    const f32x2 wih0q01 = {Wih[o0 * 2], Wih[o1 * 2]};
    const f32x2 wih0q23 = {Wih[o2 * 2], Wih[o3 * 2]};
    const f32x2 wih1q01 = {Wih[o0 * 2 + 1], Wih[o1 * 2 + 1]};
    const f32x2 wih1q23 = {Wih[o2 * 2 + 1], Wih[o3 * 2 + 1]};
    const f32x2 basbq01 = {bih[o0] + bhh[o0], bih[o1] + bhh[o1]};
    const f32x2 basbq23 = {bih[o2] + bhh[o2], bih[o3] + bhh[o3]};

    // ---- sigma0 = var(row, ddof=1) ----
    float s1 = 0.f, s2 = 0.f;
#pragma unroll 8
    for (int i = 0; i < S_LEN / 64; ++i) {
        const float x = row[i * 64 + lane];
        s1 += x;
        s2 = fmaf(x, x, s2);
    }
    s1 = wave_sum(s1);
    s2 = wave_sum(s2);
    const float mean = s1 * (1.0f / S_LEN);
    float sigma = (s2 - s1 * mean) * (1.0f / (S_LEN - 1));

    float vout = (lane == 0) ? sigma : 0.f;   // out[b][0] = sigma0

    // eps^2 double-buffer: squared once per 64-step window
    float en = row[64 + lane];
    float eq = row[lane] * row[lane];

    float* hbw = &hb[wave][0];
    const f32x4* hbq = (const f32x4*)hbw + (p << 2);  // quads 4p..4p+3
    float* hwr = &hb[wave][(p << 4) + g];             // writes h[16p+g]

    // h_0 = 0: loop-carried hq regs start at zero
    f32x4 hq0 = {0,0,0,0}, hq1 = {0,0,0,0}, hq2 = {0,0,0,0}, hq3 = {0,0,0,0};

#define MJ(M, J, HQ) { \
    acc##M = __builtin_elementwise_fma(lo2(W4[(M<<2)+J]), lo2(HQ), acc##M); \
    acc##M = __builtin_elementwise_fma(hi2(W4[(M<<2)+J]), hi2(HQ), acc##M); }

#pragma unroll 2
    for (int t = 1; t < S_LEN; ++t) {
        const int idx = (t - 1) & 63;
        if (idx == 0 && t > 1) {            // wave-uniform window advance
            eq = en * en;
            const int nb = ((t - 1) >> 6) + 1;
            if (nb < S_LEN / 64) en = row[nb * 64 + lane];
        }
        const float e2 = rlane(eq, idx);

        // ---- x_t = u.h_{t-1} + c0*e2 + c1*sigma_{t-1} + cb ----
        // (independent of h_t; chunk partials identical across g, so the
        //  reduction is just the 2 quad_perm levels -- no wave_sum)
        f32x2 up = {0.f, 0.f};
        up = __builtin_elementwise_fma(lo2(uq0), lo2(hq0), up);
        up = __builtin_elementwise_fma(hi2(uq0), hi2(hq0), up);
        up = __builtin_elementwise_fma(lo2(uq1), lo2(hq1), up);
        up = __builtin_elementwise_fma(hi2(uq1), hi2(hq1), up);
        up = __builtin_elementwise_fma(lo2(uq2), lo2(hq2), up);
        up = __builtin_elementwise_fma(hi2(uq2), hi2(hq2), up);
        up = __builtin_elementwise_fma(lo2(uq3), lo2(hq3), up);
        up = __builtin_elementwise_fma(hi2(uq3), hi2(hq3), up);
        float upart = up.x + up.y;
        upart = qp_add<0xB1>(upart);
        upart = qp_add<0x4E>(upart);
        float x = upart + fmaf(c0, e2, cb);
        x = fmaf(c1, sigma, x);               // sigma_{t-1}: 1 fma on the chain
        const float ee = __expf(-fabsf(x));
        const float nsig = fmaxf(x, 0.f) + __logf(1.0f + ee) + 1e-6f;

        // ---- h_t matvec (uses OLD sigma in epilogue) ----
        f32x2 acc0 = {0,0}, acc1 = {0,0}, acc2 = {0,0}, acc3 = {0,0};
        MJ(0,0,hq0) MJ(0,1,hq1) MJ(0,2,hq2) MJ(0,3,hq3)
        MJ(1,0,hq0) MJ(1,1,hq1) MJ(1,2,hq2) MJ(1,3,hq3)
        MJ(2,0,hq0) MJ(2,1,hq1) MJ(2,2,hq2) MJ(2,3,hq3)
        MJ(3,0,hq0) MJ(3,1,hq1) MJ(3,2,hq2) MJ(3,3,hq3)
        f32x2 y01 = {acc0.x + acc0.y, acc1.x + acc1.y};
        f32x2 y23 = {acc2.x + acc2.y, acc3.x + acc3.y};
        y01.x = qp_add<0xB1>(y01.x); y01.y = qp_add<0xB1>(y01.y);
        y23.x = qp_add<0xB1>(y23.x); y23.y = qp_add<0xB1>(y23.y);
        y01.x = qp_add<0x4E>(y01.x); y01.y = qp_add<0x4E>(y01.y);
        y23.x = qp_add<0x4E>(y23.x); y23.y = qp_add<0x4E>(y23.y);

        const f32x2 e2v = {e2, e2};
        const f32x2 sgv = {sigma, sigma};     // OLD sigma
        y01 += basbq01;
        y23 += basbq23;
        y01 = __builtin_elementwise_fma(e2v, wih0q01, y01);
        y23 = __builtin_elementwise_fma(e2v, wih0q23, y23);
        y01 = __builtin_elementwise_fma(sgv, wih1q01, y01);
        y23 = __builtin_elementwise_fma(sgv, wih1q23, y23);

        // write h[16p+g]; immediately prefetch next step's quads
        const float hvx = (lane & 2) ? y23.x : y01.x;
        const float hvy = (lane & 2) ? y23.y : y01.y;
        *hwr = (lane & 1) ? hvy : hvx;
        hq0 = hbq[0]; hq1 = hbq[1]; hq2 = hbq[2]; hq3 = hbq[3];

        sigma = nsig;

        // stage sigma_t into lane (t&63); coalesced store each 64 steps
        if ((t & 63) == lane) vout = sigma;
        if ((t & 63) == 63) orow[(t - 63) + lane] = vout;
    }
#undef MJ
}

extern "C" void kernel_launch(void* const* d_in, const int* in_sizes, int n_in,
                              void* d_out, int out_size, void* d_ws, size_t ws_size,
                              hipStream_t stream) {
    const float* res = (const float*)d_in[0];
    const float* Wih = (const float*)d_in[1];
    const float* bih = (const float*)d_in[2];
    const float* Whh = (const float*)d_in[3];
    const float* bhh = (const float*)d_in[4];
    const float* fcw = (const float*)d_in[5];
    const float* fcb = (const float*)d_in[6];
    float* out = (float*)d_out;

    const int B = 2048;
    dim3 grid(B / 4), block(256);
    hipLaunchKernelGGL(rnn_garch_kernel, grid, block, 0, stream,
                       res, Wih, bih, Whh, bhh, fcw, fcb, out);
}